// Round 2
// baseline (286.831 us; speedup 1.0000x reference)
//
#include <hip/hip_runtime.h>
#include <stdint.h>

// Problem constants
#define DIM    1024
#define RANK   16
#define M_TOT  8192          // 2*4096 rows of x
#define N_TOT  3072          // 3*DIM output features
#define K_TOT  1024

// GEMM tiling: block = 64(M) x 128(N), BK=64, 4 waves, wave tile 64x32
#define BM 64
#define BN 128
#define BK 64

typedef __attribute__((ext_vector_type(8))) short  s8v;   // 8 x bf16 (raw bits)
typedef __attribute__((ext_vector_type(4))) float  f4v;   // MFMA acc

__device__ __forceinline__ unsigned short f2bf(float f) {
    union { float f; unsigned int u; } v; v.f = f;
    unsigned int u = v.u;
    u += 0x7FFFu + ((u >> 16) & 1u);   // round-to-nearest-even
    return (unsigned short)(u >> 16);
}

// ---------------- Kernel 1: fused prep ----------------
// blocks [0, 8192):    x fp32 -> bf16 (float4 -> ushort4)
// blocks [8192, 11264): fold LoRA into W, fp32 -> bf16
__global__ void prep(const float4* __restrict__ x, ushort4* __restrict__ xb,
                     const float* __restrict__ W,
                     const float* __restrict__ Aq, const float* __restrict__ Bq,
                     const float* __restrict__ Ak, const float* __restrict__ Bk,
                     const float* __restrict__ Av, const float* __restrict__ Bv,
                     const float* __restrict__ alpha_p,
                     unsigned short* __restrict__ Wb) {
    const int tid = threadIdx.x;
    if (blockIdx.x < 8192) {
        // ---- convert x ----
        int i = blockIdx.x * 256 + tid;      // n4 = 2097152 = 8192*256 exactly
        float4 v = x[i];
        ushort4 o;
        o.x = f2bf(v.x); o.y = f2bf(v.y); o.z = f2bf(v.z); o.w = f2bf(v.w);
        xb[i] = o;
    } else {
        // ---- fold W_eff[o][d] = W[o][d] + alpha * sum_r B[o%1024][r]*A[r][d] ----
        const int o    = blockIdx.x - 8192;  // 0..3071
        const int sel  = o >> 10;            // 0=q 1=k 2=v
        const int orow = o & 1023;
        const float* Am = (sel == 0) ? Aq : (sel == 1) ? Ak : Av;  // [RANK, DIM]
        const float* Bm = (sel == 0) ? Bq : (sel == 1) ? Bk : Bv;  // [DIM, RANK]

        __shared__ float sb[RANK];
        if (tid < RANK) sb[tid] = alpha_p[0] * Bm[orow * RANK + tid];
        __syncthreads();

        for (int d = tid; d < DIM; d += 256) {
            float acc = W[o * DIM + d];
            #pragma unroll
            for (int r = 0; r < RANK; ++r)
                acc += sb[r] * Am[r * DIM + d];
            Wb[o * DIM + d] = f2bf(acc);
        }
    }
}

// ---------------- Kernel 2: bf16 MFMA GEMM, C = Xb * Wb^T + bias ----------------
// Xb: [M_TOT, K_TOT] bf16 row-major; Wb: [N_TOT, K_TOT] bf16 row-major (NT gemm)
// Block tile 64x128, BK=64. 4 waves, each computes 64(M) x 32(N): acc[4][2]
// (32 AGPRs) -> ~90 unified regs -> 5 blocks/CU resident (LDS 24KB * 5 = 120K).
// LDS: fragment-ordered 1KB chunks (lane l owns bytes [c*1024 + l*16, +16)),
// satisfying global_load_lds' wave-uniform-base + lane*16 constraint and making
// ds_read_b128 conflict-free. A tile = 8 chunks, B tile = 16 chunks; 24 total,
// 6 staged per wave per K-iter.
__global__ __launch_bounds__(256, 5)
void gemm_bt(const unsigned short* __restrict__ Xb,
             const unsigned short* __restrict__ Wb,
             const float* __restrict__ bias,
             float* __restrict__ out) {
    __shared__ __align__(16) unsigned short As[BM * BK];  //  8 KB
    __shared__ __align__(16) unsigned short Bs[BN * BK];  // 16 KB

    const int tid  = threadIdx.x;
    const int wave = tid >> 6;       // 0..3  (= wave's N quadrant)
    const int lane = tid & 63;
    const int l15  = lane & 15;
    const int lq   = lane >> 4;      // 0..3

    const int bm = blockIdx.x;       // 0..127 (M tiles of 64)
    const int bn = blockIdx.y;       // 0..23  (N tiles of 128)

    // Per-lane global staging pointers: wave stages chunks q = wave*6 .. +5
    // q < 8  -> A chunk q;  q >= 8 -> B chunk q-8
    const unsigned short* gptr[6];
    unsigned short* lptr[6];
    #pragma unroll
    for (int u = 0; u < 6; ++u) {
        const int q = wave * 6 + u;
        const int c   = (q < 8) ? q : (q - 8);
        const int row = ((c >> 1) << 4) + l15;
        const int col = ((c & 1) << 5) + (lq << 3);
        if (q < 8) {
            gptr[u] = Xb + (size_t)(bm * BM + row) * K_TOT + col;
            lptr[u] = &As[c * 512];
        } else {
            gptr[u] = Wb + (size_t)(bn * BN + row) * K_TOT + col;
            lptr[u] = &Bs[c * 512];
        }
    }

    f4v acc[4][2] = {};

    for (int kk = 0; kk < K_TOT; kk += BK) {
        __syncthreads();   // all waves done reading LDS from prev iter
        #pragma unroll
        for (int u = 0; u < 6; ++u) {
            __builtin_amdgcn_global_load_lds(
                (const __attribute__((address_space(1))) void*)(gptr[u]),
                (__attribute__((address_space(3))) void*)(lptr[u]),
                16, 0, 0);
            gptr[u] += BK;
        }
        __syncthreads();   // staging landed

        const s8v* Avp = (const s8v*)As;
        const s8v* Bvp = (const s8v*)Bs;
        #pragma unroll
        for (int t = 0; t < 2; ++t) {          // two k-steps of 32 within BK=64
            s8v af[4], bf[2];
            #pragma unroll
            for (int i = 0; i < 4; ++i)
                af[i] = Avp[(i * 2 + t) * 64 + lane];
            #pragma unroll
            for (int j = 0; j < 2; ++j)
                bf[j] = Bvp[((wave * 2 + j) * 2 + t) * 64 + lane];
            #pragma unroll
            for (int i = 0; i < 4; ++i)
                #pragma unroll
                for (int j = 0; j < 2; ++j)
                    acc[i][j] = __builtin_amdgcn_mfma_f32_16x16x32_bf16(
                        af[i], bf[j], acc[i][j], 0, 0, 0);
        }
    }

    // Epilogue: C/D layout col = lane&15, row = (lane>>4)*4 + reg  [m89]
    #pragma unroll
    for (int j = 0; j < 2; ++j) {
        const int col = bn * BN + wave * 32 + j * 16 + l15;
        const float bv = bias[col];
        #pragma unroll
        for (int i = 0; i < 4; ++i) {
            const int row0 = bm * BM + i * 16 + lq * 4;
            #pragma unroll
            for (int r = 0; r < 4; ++r)
                out[(size_t)(row0 + r) * N_TOT + col] = acc[i][j][r] + bv;
        }
    }
}

extern "C" void kernel_launch(void* const* d_in, const int* in_sizes, int n_in,
                              void* d_out, int out_size, void* d_ws, size_t ws_size,
                              hipStream_t stream) {
    const float* x     = (const float*)d_in[0];   // [2,4096,1024]
    const float* W     = (const float*)d_in[1];   // [3072,1024]
    const float* b     = (const float*)d_in[2];   // [3072]
    const float* Aq    = (const float*)d_in[3];
    const float* Bq    = (const float*)d_in[4];
    const float* Ak    = (const float*)d_in[5];
    const float* Bk    = (const float*)d_in[6];
    const float* Av    = (const float*)d_in[7];
    const float* Bv    = (const float*)d_in[8];
    const float* alpha = (const float*)d_in[9];
    float* out = (float*)d_out;

    unsigned short* xb = (unsigned short*)d_ws;                                      // 16 MB
    unsigned short* Wb = (unsigned short*)((char*)d_ws + (size_t)M_TOT * K_TOT * 2); // +6 MB

    prep<<<8192 + N_TOT, 256, 0, stream>>>((const float4*)x, (ushort4*)xb,
                                           W, Aq, Bq, Ak, Bk, Av, Bv, alpha, Wb);

    dim3 grid(M_TOT / BM, N_TOT / BN);    // 128 x 24 = 3072 blocks
    gemm_bt<<<grid, 256, 0, stream>>>(xb, Wb, b, out);
}

// Round 3
// 244.498 us; speedup vs baseline: 1.1731x; 1.1731x over previous
//
#include <hip/hip_runtime.h>
#include <stdint.h>

// Problem constants
#define DIM    1024
#define RANK   16
#define M_TOT  8192          // 2*4096 rows of x
#define N_TOT  3072          // 3*DIM output features
#define K_TOT  1024

// GEMM tiling: block = 128x128, BK=64, 4 waves, wave tile 64x64 (acc 4x4)
#define BM 128
#define BN 128
#define BK 64

typedef __attribute__((ext_vector_type(8))) short  s8v;   // 8 x bf16 (raw bits)
typedef __attribute__((ext_vector_type(4))) float  f4v;   // MFMA acc

__device__ __forceinline__ unsigned short f2bf(float f) {
    union { float f; unsigned int u; } v; v.f = f;
    unsigned int u = v.u;
    u += 0x7FFFu + ((u >> 16) & 1u);   // round-to-nearest-even
    return (unsigned short)(u >> 16);
}

// ---------------- Kernel 1: fused prep ----------------
// blocks [0, 8192):     x fp32 -> bf16 (float4 -> ushort4)
// blocks [8192, 11264): fold LoRA into W, fp32 -> bf16
__global__ void prep(const float4* __restrict__ x, ushort4* __restrict__ xb,
                     const float* __restrict__ W,
                     const float* __restrict__ Aq, const float* __restrict__ Bq,
                     const float* __restrict__ Ak, const float* __restrict__ Bk,
                     const float* __restrict__ Av, const float* __restrict__ Bv,
                     const float* __restrict__ alpha_p,
                     unsigned short* __restrict__ Wb) {
    const int tid = threadIdx.x;
    if (blockIdx.x < 8192) {
        int i = blockIdx.x * 256 + tid;      // n4 = 2097152 = 8192*256 exactly
        float4 v = x[i];
        ushort4 o;
        o.x = f2bf(v.x); o.y = f2bf(v.y); o.z = f2bf(v.z); o.w = f2bf(v.w);
        xb[i] = o;
    } else {
        const int o    = blockIdx.x - 8192;  // 0..3071
        const int sel  = o >> 10;            // 0=q 1=k 2=v
        const int orow = o & 1023;
        const float* Am = (sel == 0) ? Aq : (sel == 1) ? Ak : Av;  // [RANK, DIM]
        const float* Bm = (sel == 0) ? Bq : (sel == 1) ? Bk : Bv;  // [DIM, RANK]

        __shared__ float sb[RANK];
        if (tid < RANK) sb[tid] = alpha_p[0] * Bm[orow * RANK + tid];
        __syncthreads();

        for (int d = tid; d < DIM; d += 256) {
            float acc = W[o * DIM + d];
            #pragma unroll
            for (int r = 0; r < RANK; ++r)
                acc += sb[r] * Am[r * DIM + d];
            Wb[o * DIM + d] = f2bf(acc);
        }
    }
}

// ---------------- Kernel 2: bf16 MFMA GEMM, C = Xb * Wb^T + bias ----------------
// Register-prefetch pipeline: global->VGPR loads for tile k+1 are issued right
// after tile k's LDS-publish barrier and consumed (ds_write) only after the
// next barrier -- one full compute phase of slack hides the L2 latency, so the
// vmcnt wait at ds_write is near-free (the round-1 structure sat on a naked
// vmcnt(0) drain between its two barriers every iter -> MfmaUtil 18%).
// LDS: fragment-ordered 1KB chunks (lane l owns halves [c*512 + l*8, +8)),
// conflict-free for both ds_write_b128 and ds_read_b128.
__global__ __launch_bounds__(256, 3)
void gemm_bt(const unsigned short* __restrict__ Xb,
             const unsigned short* __restrict__ Wb,
             const float* __restrict__ bias,
             float* __restrict__ out) {
    __shared__ __align__(16) unsigned short As[BM * BK];  // 16 KB, 16 chunks
    __shared__ __align__(16) unsigned short Bs[BN * BK];  // 16 KB, 16 chunks

    const int tid  = threadIdx.x;
    const int wave = tid >> 6;       // 0..3
    const int lane = tid & 63;
    const int l15  = lane & 15;
    const int lq   = lane >> 4;      // 0..3
    const int wr   = wave >> 1;      // wave row quadrant (0..1)
    const int wc   = wave & 1;       // wave col quadrant (0..1)

    const int bm = blockIdx.x;       // 0..63   (M tiles)
    const int bn = blockIdx.y;       // 0..23   (N tiles)

    // Wave stages A chunks wave*4..+3 and B chunks wave*4..+3.
    // Chunk c: rows (c>>1)*16 + l15, k-cols (c&1)*32 + lq*8 (8 halves / lane).
    const unsigned short* aptr[4];
    const unsigned short* bptr[4];
    unsigned short* alds[4];
    unsigned short* blds[4];
    #pragma unroll
    for (int u = 0; u < 4; ++u) {
        const int c   = wave * 4 + u;
        const int row = ((c >> 1) << 4) + l15;       // 0..127
        const int col = ((c & 1) << 5) + (lq << 3);  // 0..56
        aptr[u] = Xb + (size_t)(bm * BM + row) * K_TOT + col;
        bptr[u] = Wb + (size_t)(bn * BN + row) * K_TOT + col;
        alds[u] = &As[c * 512 + lane * 8];
        blds[u] = &Bs[c * 512 + lane * 8];
    }

    // Prologue: prefetch tile kk=0 into registers
    s8v areg[4], breg[4];
    #pragma unroll
    for (int u = 0; u < 4; ++u) {
        areg[u] = *(const s8v*)(aptr[u]);
        breg[u] = *(const s8v*)(bptr[u]);
    }

    f4v acc[4][4] = {};

    for (int kk = 0; kk < K_TOT; kk += BK) {
        __syncthreads();   // all waves done reading LDS from prev iter
        #pragma unroll
        for (int u = 0; u < 4; ++u) {
            *(s8v*)(alds[u]) = areg[u];   // waits vmcnt for the prefetch here
            *(s8v*)(blds[u]) = breg[u];
        }
        __syncthreads();   // LDS tile published

        // Issue next tile's loads NOW; consumed only after the next barrier.
        const int kn = (kk + BK < K_TOT) ? (kk + BK) : 0;  // wrap: harmless reload
        #pragma unroll
        for (int u = 0; u < 4; ++u) {
            areg[u] = *(const s8v*)(aptr[u] + kn);
            breg[u] = *(const s8v*)(bptr[u] + kn);
        }

        const s8v* Avp = (const s8v*)As;
        const s8v* Bvp = (const s8v*)Bs;
        #pragma unroll
        for (int t = 0; t < 2; ++t) {          // two k-steps of 32 within BK=64
            s8v af[4], bf[4];
            #pragma unroll
            for (int i = 0; i < 4; ++i) {
                const int ia = wr * 4 + i;     // A row-tile index 0..7
                const int jb = wc * 4 + i;     // B row-tile index 0..7
                af[i] = Avp[(ia * 2 + t) * 64 + lane];
                bf[i] = Bvp[(jb * 2 + t) * 64 + lane];
            }
            #pragma unroll
            for (int i = 0; i < 4; ++i)
                #pragma unroll
                for (int j = 0; j < 4; ++j)
                    acc[i][j] = __builtin_amdgcn_mfma_f32_16x16x32_bf16(
                        af[i], bf[j], acc[i][j], 0, 0, 0);
        }
    }

    // Epilogue: C/D layout col = lane&15, row = (lane>>4)*4 + reg  [m89]
    const int col_base = bn * BN + wc * 64;
    const int row_base = bm * BM + wr * 64 + lq * 4;
    #pragma unroll
    for (int j = 0; j < 4; ++j) {
        const int col = col_base + j * 16 + l15;
        const float bv = bias[col];
        #pragma unroll
        for (int i = 0; i < 4; ++i) {
            const int row = row_base + i * 16;
            #pragma unroll
            for (int r = 0; r < 4; ++r)
                out[(size_t)(row + r) * N_TOT + col] = acc[i][j][r] + bv;
        }
    }
}

extern "C" void kernel_launch(void* const* d_in, const int* in_sizes, int n_in,
                              void* d_out, int out_size, void* d_ws, size_t ws_size,
                              hipStream_t stream) {
    const float* x     = (const float*)d_in[0];   // [2,4096,1024]
    const float* W     = (const float*)d_in[1];   // [3072,1024]
    const float* b     = (const float*)d_in[2];   // [3072]
    const float* Aq    = (const float*)d_in[3];
    const float* Bq    = (const float*)d_in[4];
    const float* Ak    = (const float*)d_in[5];
    const float* Bk    = (const float*)d_in[6];
    const float* Av    = (const float*)d_in[7];
    const float* Bv    = (const float*)d_in[8];
    const float* alpha = (const float*)d_in[9];
    float* out = (float*)d_out;

    unsigned short* xb = (unsigned short*)d_ws;                                      // 16 MB
    unsigned short* Wb = (unsigned short*)((char*)d_ws + (size_t)M_TOT * K_TOT * 2); // +6 MB

    prep<<<8192 + N_TOT, 256, 0, stream>>>((const float4*)x, (ushort4*)xb,
                                           W, Aq, Bq, Ak, Bk, Av, Bv, alpha, Wb);

    dim3 grid(M_TOT / BM, N_TOT / BN);    // 64 x 24 = 1536 blocks
    gemm_bt<<<grid, 256, 0, stream>>>(xb, Wb, b, out);
}